// Round 1
// 829.750 us; speedup vs baseline: 1.2773x; 1.2773x over previous
//
#include <hip/hip_runtime.h>

typedef unsigned short u16;
typedef __bf16 bf16x8 __attribute__((ext_vector_type(8)));
typedef float f32x4 __attribute__((ext_vector_type(4)));

__device__ __forceinline__ float bf2f(u16 u) {
  union { unsigned int i; float f; } v; v.i = ((unsigned int)u) << 16; return v.f;
}
__device__ __forceinline__ u16 f2bf(float f) {
  union { float f; unsigned int i; } v; v.f = f;
  unsigned int i = v.i;
  return (u16)((i + 0x7fffu + ((i >> 16) & 1u)) >> 16);  // RNE
}
__device__ __forceinline__ float ldf(const float* p) { return *p; }
__device__ __forceinline__ float ldf(const u16* p) { return bf2f(*p); }

// ---------------- weight transpose + cast: Wt[n*K+k] = bf16(W[k*N+n]) ----
__global__ void transpose_kernel(const float* __restrict__ W, u16* __restrict__ Wt,
                                 int K, int N) {
  int idx = blockIdx.x * 256 + threadIdx.x;
  if (idx >= K * N) return;
  int k = idx / N, n = idx % N;
  Wt[n * K + k] = f2bf(W[idx]);
}

// ---------------- layernorm over C=576, 4 rows/block (1 wave each) -------
template <typename T>
__global__ __launch_bounds__(256) void ln_kernel(const T* __restrict__ x,
                                                 const float* __restrict__ w,
                                                 const float* __restrict__ b,
                                                 u16* __restrict__ out) {
  int wave = threadIdx.x >> 6, lane = threadIdx.x & 63;
  long row = (long)blockIdx.x * 4 + wave;
  const T* xr = x + row * 576;
  float v[9];
  float sum = 0.f;
  #pragma unroll
  for (int i = 0; i < 9; ++i) { v[i] = ldf(&xr[lane + i * 64]); sum += v[i]; }
  #pragma unroll
  for (int off = 32; off; off >>= 1) sum += __shfl_xor(sum, off);
  float mean = sum * (1.0f / 576.0f);
  float var = 0.f;
  #pragma unroll
  for (int i = 0; i < 9; ++i) { float d = v[i] - mean; var += d * d; }
  #pragma unroll
  for (int off = 32; off; off >>= 1) var += __shfl_xor(var, off);
  float rstd = rsqrtf(var * (1.0f / 576.0f) + 1e-5f);
  u16* outr = out + row * 576;
  #pragma unroll
  for (int i = 0; i < 9; ++i) {
    int c = lane + i * 64;
    outr[c] = f2bf((v[i] - mean) * rstd * w[c] + b[c]);
  }
}

// ---------------- DMlp gather: pixelshuffle(3) + reflpad(2) + masked unfold
// chunk-local: ln2 points at chunk start (whole batches), b chunk-relative.
__constant__ int c_di[25] = {0,0,0, 1,1,1, 2,2,2, 3,3,3,3,3,3,3, 4,4,4, 5,5,5, 6,6,6};
__constant__ int c_dj[25] = {0,3,6, 1,3,5, 2,3,4, 0,1,2,3,4,5,6, 2,3,4, 1,3,5, 0,3,6};

__device__ __forceinline__ int refl168(int t) {
  return t < 0 ? -t : (t >= 168 ? 334 - t : t);
}

__global__ __launch_bounds__(256) void gather_kernel(const u16* __restrict__ ln2,
                                                     u16* __restrict__ cols) {
  int idx = blockIdx.x * 256 + threadIdx.x;
  int f = idx % 1600;
  int n_ = idx / 1600;            // b*3136 + i*56 + j  (b chunk-relative)
  int bj = n_ % 3136, b = n_ / 3136;
  int i = bj / 56, j = bj % 56;
  int p = f % 25, nf = f / 25;
  int R  = refl168(c_di[p] + 3 * i - 2);
  int Cc = refl168(c_dj[p] + 3 * j - 2);
  int h2 = R / 3, a = R - 3 * h2;
  int w2 = Cc / 3, b2 = Cc - 3 * w2;
  long src = ((long)b * 3136 + h2 * 56 + w2) * 576 + nf * 9 + a * 3 + b2;
  cols[idx] = ln2[src];
}

// ---------------- window attention, MFMA version -------------------------
// one block per (window, head); 4 waves. QK^T and PV via mfma_f32_16x16x32_bf16
// with the same fragment mapping as gemm_kernel below (A[M,K] row-major,
// B[N,K] row-major, C row = quad*4+r, col = nt*16+l15).
// S rows/cols padded 49->64; pad cells masked to -inf pre-softmax (also kills
// NaN from uninitialized LDS pad rows); Vt pad cols zeroed.
__global__ __launch_bounds__(256) void attn_kernel(const u16* __restrict__ qkv,
                                                   const float* __restrict__ rpb,
                                                   u16* __restrict__ obuf) {
  int h = blockIdx.y;            // 0..5
  int wi = blockIdx.x;
  int b = wi >> 6, w = wi & 63, wr = w >> 3, wc = w & 7;
  __shared__ __align__(16) u16 Qs[64 * 104];   // [t][d] stride 104 (16B-aligned rows)
  __shared__ __align__(16) u16 Ks[64 * 104];
  __shared__ __align__(16) u16 Vt[96 * 72];    // [d][t] transposed, cols 49..63 zeroed
  __shared__ __align__(16) u16 Ps[64 * 72];    // P bf16, [i][j], pad cols exactly 0
  int tid = threadIdx.x;
  int lane = tid & 63, wv = tid >> 6;
  int quad = lane >> 4, l15 = lane & 15;
  const float scale = 0.1020620726159658f;  // 96^-0.5

  long base = ((long)b * 3136 + wr * 7 * 56 + wc * 7) * 1728 + h * 96;

  // stage Q,K: coalesced uint4 (dq fastest), conflict-free b128 writes
  for (int idx = tid; idx < 588; idx += 256) {
    int t = idx / 12, dq = idx % 12;
    int tr = t / 7, tc = t - tr * 7;
    long roff = base + (tr * 56 + tc) * 1728 + dq * 8;
    *(uint4*)&Qs[t * 104 + dq * 8] = *(const uint4*)(qkv + roff);
    *(uint4*)&Ks[t * 104 + dq * 8] = *(const uint4*)(qkv + roff + 576);
  }
  // Vt pad cols (j = 49..63) must be 0: they multiply Ps pad cols (0) in MFMA
  for (int idx = tid; idx < 96 * 15; idx += 256) {
    int d = idx / 15, t = 49 + idx % 15;
    Vt[d * 72 + t] = 0;
  }
  // stage V transposed: t-fastest lane mapping -> conflict-free u16 LDS writes
  // (global side is 16B-gather; L2-resident, latency-hidden)
  for (int idx = tid; idx < 768; idx += 256) {
    int dq = idx >> 6, t = idx & 63;
    if (t < 49) {
      int tr = t / 7, tc = t - tr * 7;
      uint4 v = *(const uint4*)(qkv + base + (tr * 56 + tc) * 1728 + 1152 + dq * 8);
      const u16* vv = (const u16*)&v;
      #pragma unroll
      for (int kk = 0; kk < 8; ++kk) Vt[(dq * 8 + kk) * 72 + t] = vv[kk];
    }
  }
  __syncthreads();

  // ---- QK^T: wave wv owns S rows [wv*16, wv*16+16) ----
  f32x4 accS[4] = {};
  #pragma unroll
  for (int k0 = 0; k0 < 3; ++k0) {
    bf16x8 aq = *(const bf16x8*)&Qs[(wv * 16 + l15) * 104 + k0 * 32 + quad * 8];
    #pragma unroll
    for (int nt = 0; nt < 4; ++nt) {
      bf16x8 bk = *(const bf16x8*)&Ks[(nt * 16 + l15) * 104 + k0 * 32 + quad * 8];
      accS[nt] = __builtin_amdgcn_mfma_f32_16x16x32_bf16(aq, bk, accS[nt], 0, 0, 0);
    }
  }

  // ---- softmax fully in-register: row r lives in the 16 lanes of one quad ----
  #pragma unroll
  for (int r = 0; r < 4; ++r) {
    int rg = wv * 16 + quad * 4 + r;          // global window-row (0..63)
    int yi = rg / 7, xi = rg - yi * 7;
    float sv[4];
    float mx = -3e38f;
    #pragma unroll
    for (int nt = 0; nt < 4; ++nt) {
      int col = nt * 16 + l15;
      float s = accS[nt][r] * scale;
      if (rg < 49 && col < 49) {
        int yj = col / 7, xj = col - yj * 7;
        s += rpb[((yi - yj + 6) * 13 + (xi - xj + 6)) * 6 + h];
      } else {
        s = -3e38f;                            // masks pad cols AND any NaN from pad LDS
      }
      sv[nt] = s;
      mx = fmaxf(mx, s);
    }
    #pragma unroll
    for (int off = 8; off; off >>= 1) mx = fmaxf(mx, __shfl_xor(mx, off));
    float sum = 0.f;
    #pragma unroll
    for (int nt = 0; nt < 4; ++nt) { sv[nt] = __expf(sv[nt] - mx); sum += sv[nt]; }
    #pragma unroll
    for (int off = 8; off; off >>= 1) sum += __shfl_xor(sum, off);
    float inv = 1.0f / sum;
    u16* psr = Ps + rg * 72;
    #pragma unroll
    for (int nt = 0; nt < 4; ++nt) psr[nt * 16 + l15] = f2bf(sv[nt] * inv);
  }
  __syncthreads();

  // ---- PV: O[i][d] = sum_j P[i][j] * Vt[d][j], K-dim = 64 (pad zeroed) ----
  f32x4 accO[6] = {};
  #pragma unroll
  for (int k0 = 0; k0 < 2; ++k0) {
    bf16x8 ap = *(const bf16x8*)&Ps[(wv * 16 + l15) * 72 + k0 * 32 + quad * 8];
    #pragma unroll
    for (int nt = 0; nt < 6; ++nt) {
      bf16x8 bv = *(const bf16x8*)&Vt[(nt * 16 + l15) * 72 + k0 * 32 + quad * 8];
      accO[nt] = __builtin_amdgcn_mfma_f32_16x16x32_bf16(ap, bv, accO[nt], 0, 0, 0);
    }
  }
  #pragma unroll
  for (int r = 0; r < 4; ++r) {
    int rg = wv * 16 + quad * 4 + r;
    if (rg < 49) {
      int tr = rg / 7, tc = rg - tr * 7;
      long ooff = ((long)b * 3136 + (wr * 7 + tr) * 56 + wc * 7 + tc) * 576 + h * 96;
      #pragma unroll
      for (int nt = 0; nt < 6; ++nt) obuf[ooff + nt * 16 + l15] = f2bf(accO[nt][r]);
    }
  }
}

// ---------------- bf16 MFMA GEMM: C(M,N) = A(M,K) @ Bt(N,K)^T + epi ------
// tile 128x64x32, 256 threads (4 waves)
// EPI: 0 = +bias ; 1 = +bias, exact GELU ; 2 = +bias, +res
// TR: residual elem type (float or u16). TO: output elem type (u16 or float).
template <int EPI, typename TR, typename TO>
__global__ __launch_bounds__(256) void gemm_kernel(const u16* __restrict__ A,
                                                   const u16* __restrict__ Bt,
                                                   const float* __restrict__ bias,
                                                   const TR* __restrict__ res,
                                                   TO* __restrict__ C,
                                                   int M, int N, int K) {
  __shared__ u16 As[128 * 40];
  __shared__ u16 Bs[64 * 40];
  int n0 = blockIdx.x * 64;
  int m0 = blockIdx.y * 128;
  int tid = threadIdx.x;
  int lane = tid & 63, wv = tid >> 6;
  int quad = lane >> 4, l15 = lane & 15;
  f32x4 acc[2][4] = {};

  for (int k0 = 0; k0 < K; k0 += 32) {
    #pragma unroll
    for (int it = 0; it < 2; ++it) {
      int idx = (tid + it * 256) * 8;
      int r = idx >> 5, kk = idx & 31;
      uint4 v = *(const uint4*)(A + (long)(m0 + r) * K + k0 + kk);
      *(uint4*)(&As[r * 40 + kk]) = v;
    }
    {
      int idx = tid * 8;
      int r = idx >> 5, kk = idx & 31;
      uint4 v = *(const uint4*)(Bt + (long)(n0 + r) * K + k0 + kk);
      *(uint4*)(&Bs[r * 40 + kk]) = v;
    }
    __syncthreads();
    bf16x8 a0 = *(const bf16x8*)(&As[(wv * 32 + l15) * 40 + quad * 8]);
    bf16x8 a1 = *(const bf16x8*)(&As[(wv * 32 + 16 + l15) * 40 + quad * 8]);
    #pragma unroll
    for (int nt = 0; nt < 4; ++nt) {
      bf16x8 bf = *(const bf16x8*)(&Bs[(nt * 16 + l15) * 40 + quad * 8]);
      acc[0][nt] = __builtin_amdgcn_mfma_f32_16x16x32_bf16(a0, bf, acc[0][nt], 0, 0, 0);
      acc[1][nt] = __builtin_amdgcn_mfma_f32_16x16x32_bf16(a1, bf, acc[1][nt], 0, 0, 0);
    }
    __syncthreads();
  }
  #pragma unroll
  for (int mt = 0; mt < 2; ++mt)
    #pragma unroll
    for (int nt = 0; nt < 4; ++nt)
      #pragma unroll
      for (int r = 0; r < 4; ++r) {
        int row = m0 + wv * 32 + mt * 16 + quad * 4 + r;
        int col = n0 + nt * 16 + l15;
        float v = acc[mt][nt][r] + bias[col];
        if (EPI == 1) v = 0.5f * v * (1.0f + erff(v * 0.70710678118654752f));
        if (EPI == 2) v += ldf(&res[(long)row * N + col]);
        long off = (long)row * N + col;
        if (sizeof(TO) == 2) ((u16*)C)[off] = f2bf(v);
        else                 ((float*)C)[off] = v;
      }
}

// ---------------- host launch -------------------------------------------
// Inputs fp32, OUTPUT FP32 (round-5 forensics). ws peak ~93.8 MB.
// phase 1 (ln1/qkv/attn/proj) in 2 batch-halves, phase 2 in 4 batch-quarters.
extern "C" void kernel_launch(void* const* d_in, const int* in_sizes, int n_in,
                              void* d_out, int out_size, void* d_ws, size_t ws_size,
                              hipStream_t stream) {
  const float* x      = (const float*)d_in[0];
  const float* n1w    = (const float*)d_in[1];
  const float* n1b    = (const float*)d_in[2];
  const float* qkv_w  = (const float*)d_in[3];
  const float* qkv_b  = (const float*)d_in[4];
  const float* rpb    = (const float*)d_in[5];
  const float* proj_w = (const float*)d_in[6];
  const float* proj_b = (const float*)d_in[7];
  const float* n2w    = (const float*)d_in[8];
  const float* n2b    = (const float*)d_in[9];
  const float* fc1_w  = (const float*)d_in[10];
  const float* fc1_b  = (const float*)d_in[11];
  const float* fc2_w  = (const float*)d_in[12];
  const float* fc2_b  = (const float*)d_in[13];

  char* ws = (char*)d_ws;
  u16* wt_qkv  = (u16*)(ws + 0);           // 1728x576
  u16* wt_proj = (u16*)(ws + 1990656);     // 576x576
  u16* wt_fc1  = (u16*)(ws + 2654208);     // 1024x1600
  u16* wt_fc2  = (u16*)(ws + 5931008);     // 576x1024
  char* qkvpool = ws + 7110656;            // 43,352,064 B (12544x1728 bf16)
  char* lnpool  = ws + 50462720;           // 14,450,688 B (12544x576 bf16)
  u16* x1buf    = (u16*)(ws + 64913408);   // 25088x576 bf16 (end 93,814,784)

  transpose_kernel<<<3888, 256, 0, stream>>>(qkv_w, wt_qkv, 576, 1728);
  transpose_kernel<<<1296, 256, 0, stream>>>(proj_w, wt_proj, 576, 576);
  transpose_kernel<<<6400, 256, 0, stream>>>(fc1_w, wt_fc1, 1600, 1024);
  transpose_kernel<<<2304, 256, 0, stream>>>(fc2_w, wt_fc2, 1024, 576);

  // ---------- phase 1: two halves of 4 batches (12544 rows) ----------
  for (int h = 0; h < 2; ++h) {
    const long r0 = (long)h * 12544;
    u16* lnb  = (u16*)lnpool;          // ln1 out, then reused as attn out
    u16* qkvb = (u16*)qkvpool;
    ln_kernel<float><<<3136, 256, 0, stream>>>(x + r0 * 576, n1w, n1b, lnb);
    gemm_kernel<0, float, u16><<<dim3(27, 98), 256, 0, stream>>>(
        lnb, wt_qkv, qkv_b, (const float*)nullptr, qkvb, 12544, 1728, 576);
    attn_kernel<<<dim3(256, 6), 256, 0, stream>>>(qkvb, rpb, lnb);
    gemm_kernel<2, float, u16><<<dim3(9, 98), 256, 0, stream>>>(
        lnb, wt_proj, proj_b, x + r0 * 576, x1buf + r0 * 576, 12544, 576, 576);
  }

  // ---------- phase 2: four quarters of 2 batches (6272 rows) ----------
  for (int q = 0; q < 4; ++q) {
    const long r0 = (long)q * 6272;
    u16* ln2b  = (u16*)lnpool;                    //  7,225,344 B
    u16* colsb = (u16*)qkvpool;                   // 20,070,400 B
    u16* hb    = (u16*)(qkvpool + 20070400);      // 12,845,056 B
    ln_kernel<u16><<<1568, 256, 0, stream>>>(x1buf + r0 * 576, n2w, n2b, ln2b);
    gather_kernel<<<39200, 256, 0, stream>>>(ln2b, colsb);
    gemm_kernel<1, float, u16><<<dim3(16, 49), 256, 0, stream>>>(
        colsb, wt_fc1, fc1_b, (const float*)nullptr, hb, 6272, 1024, 1600);
    gemm_kernel<2, u16, float><<<dim3(9, 49), 256, 0, stream>>>(
        hb, wt_fc2, fc2_b, x1buf + r0 * 576, (float*)d_out + r0 * 576,
        6272, 576, 1024);
  }
}

// Round 2
// 821.301 us; speedup vs baseline: 1.2905x; 1.0103x over previous
//
#include <hip/hip_runtime.h>

typedef unsigned short u16;
typedef __bf16 bf16x8 __attribute__((ext_vector_type(8)));
typedef float f32x4 __attribute__((ext_vector_type(4)));

__device__ __forceinline__ float bf2f(u16 u) {
  union { unsigned int i; float f; } v; v.i = ((unsigned int)u) << 16; return v.f;
}
__device__ __forceinline__ u16 f2bf(float f) {
  union { float f; unsigned int i; } v; v.f = f;
  unsigned int i = v.i;
  return (u16)((i + 0x7fffu + ((i >> 16) & 1u)) >> 16);  // RNE
}
__device__ __forceinline__ float ldf(const float* p) { return *p; }
__device__ __forceinline__ float ldf(const u16* p) { return bf2f(*p); }

// async global->LDS, 16B per lane. LDS dest must be the wave-uniform base;
// HW writes base + lane*16 (guide §5: m97/m104).
__device__ __forceinline__ void load_lds16(const u16* g, u16* l) {
  __builtin_amdgcn_global_load_lds(
      (const __attribute__((address_space(1))) unsigned int*)g,
      (__attribute__((address_space(3))) unsigned int*)l, 16, 0, 0);
}

// ---------------- weight transpose + cast: Wt[n*K+k] = bf16(W[k*N+n]) ----
__global__ void transpose_kernel(const float* __restrict__ W, u16* __restrict__ Wt,
                                 int K, int N) {
  int idx = blockIdx.x * 256 + threadIdx.x;
  if (idx >= K * N) return;
  int k = idx / N, n = idx % N;
  Wt[n * K + k] = f2bf(W[idx]);
}

// ---------------- layernorm over C=576, 4 rows/block (1 wave each) -------
template <typename T>
__global__ __launch_bounds__(256) void ln_kernel(const T* __restrict__ x,
                                                 const float* __restrict__ w,
                                                 const float* __restrict__ b,
                                                 u16* __restrict__ out) {
  int wave = threadIdx.x >> 6, lane = threadIdx.x & 63;
  long row = (long)blockIdx.x * 4 + wave;
  const T* xr = x + row * 576;
  float v[9];
  float sum = 0.f;
  #pragma unroll
  for (int i = 0; i < 9; ++i) { v[i] = ldf(&xr[lane + i * 64]); sum += v[i]; }
  #pragma unroll
  for (int off = 32; off; off >>= 1) sum += __shfl_xor(sum, off);
  float mean = sum * (1.0f / 576.0f);
  float var = 0.f;
  #pragma unroll
  for (int i = 0; i < 9; ++i) { float d = v[i] - mean; var += d * d; }
  #pragma unroll
  for (int off = 32; off; off >>= 1) var += __shfl_xor(var, off);
  float rstd = rsqrtf(var * (1.0f / 576.0f) + 1e-5f);
  u16* outr = out + row * 576;
  #pragma unroll
  for (int i = 0; i < 9; ++i) {
    int c = lane + i * 64;
    outr[c] = f2bf((v[i] - mean) * rstd * w[c] + b[c]);
  }
}

// ---------------- DMlp gather: pixelshuffle(3) + reflpad(2) + masked unfold
// chunk-local: ln2 points at chunk start (whole batches), b chunk-relative.
__constant__ int c_di[25] = {0,0,0, 1,1,1, 2,2,2, 3,3,3,3,3,3,3, 4,4,4, 5,5,5, 6,6,6};
__constant__ int c_dj[25] = {0,3,6, 1,3,5, 2,3,4, 0,1,2,3,4,5,6, 2,3,4, 1,3,5, 0,3,6};

__device__ __forceinline__ int refl168(int t) {
  return t < 0 ? -t : (t >= 168 ? 334 - t : t);
}

__global__ __launch_bounds__(256) void gather_kernel(const u16* __restrict__ ln2,
                                                     u16* __restrict__ cols) {
  int idx = blockIdx.x * 256 + threadIdx.x;
  int f = idx % 1600;
  int n_ = idx / 1600;            // b*3136 + i*56 + j  (b chunk-relative)
  int bj = n_ % 3136, b = n_ / 3136;
  int i = bj / 56, j = bj % 56;
  int p = f % 25, nf = f / 25;
  int R  = refl168(c_di[p] + 3 * i - 2);
  int Cc = refl168(c_dj[p] + 3 * j - 2);
  int h2 = R / 3, a = R - 3 * h2;
  int w2 = Cc / 3, b2 = Cc - 3 * w2;
  long src = ((long)b * 3136 + h2 * 56 + w2) * 576 + nf * 9 + a * 3 + b2;
  cols[idx] = ln2[src];
}

// ---------------- window attention, MFMA version -------------------------
// one block per (window, head); 4 waves. QK^T and PV via mfma_f32_16x16x32_bf16
__global__ __launch_bounds__(256) void attn_kernel(const u16* __restrict__ qkv,
                                                   const float* __restrict__ rpb,
                                                   u16* __restrict__ obuf) {
  int h = blockIdx.y;            // 0..5
  int wi = blockIdx.x;
  int b = wi >> 6, w = wi & 63, wr = w >> 3, wc = w & 7;
  __shared__ __align__(16) u16 Qs[64 * 104];   // [t][d] stride 104 (16B-aligned rows)
  __shared__ __align__(16) u16 Ks[64 * 104];
  __shared__ __align__(16) u16 Vt[96 * 72];    // [d][t] transposed, cols 49..63 zeroed
  __shared__ __align__(16) u16 Ps[64 * 72];    // P bf16, [i][j], pad cols exactly 0
  int tid = threadIdx.x;
  int lane = tid & 63, wv = tid >> 6;
  int quad = lane >> 4, l15 = lane & 15;
  const float scale = 0.1020620726159658f;  // 96^-0.5

  long base = ((long)b * 3136 + wr * 7 * 56 + wc * 7) * 1728 + h * 96;

  // stage Q,K: coalesced uint4 (dq fastest), conflict-free b128 writes
  for (int idx = tid; idx < 588; idx += 256) {
    int t = idx / 12, dq = idx % 12;
    int tr = t / 7, tc = t - tr * 7;
    long roff = base + (tr * 56 + tc) * 1728 + dq * 8;
    *(uint4*)&Qs[t * 104 + dq * 8] = *(const uint4*)(qkv + roff);
    *(uint4*)&Ks[t * 104 + dq * 8] = *(const uint4*)(qkv + roff + 576);
  }
  // Vt pad cols (j = 49..63) must be 0: they multiply Ps pad cols (0) in MFMA
  for (int idx = tid; idx < 96 * 15; idx += 256) {
    int d = idx / 15, t = 49 + idx % 15;
    Vt[d * 72 + t] = 0;
  }
  // stage V transposed: t-fastest lane mapping -> conflict-free u16 LDS writes
  for (int idx = tid; idx < 768; idx += 256) {
    int dq = idx >> 6, t = idx & 63;
    if (t < 49) {
      int tr = t / 7, tc = t - tr * 7;
      uint4 v = *(const uint4*)(qkv + base + (tr * 56 + tc) * 1728 + 1152 + dq * 8);
      const u16* vv = (const u16*)&v;
      #pragma unroll
      for (int kk = 0; kk < 8; ++kk) Vt[(dq * 8 + kk) * 72 + t] = vv[kk];
    }
  }
  __syncthreads();

  // ---- QK^T: wave wv owns S rows [wv*16, wv*16+16) ----
  f32x4 accS[4] = {};
  #pragma unroll
  for (int k0 = 0; k0 < 3; ++k0) {
    bf16x8 aq = *(const bf16x8*)&Qs[(wv * 16 + l15) * 104 + k0 * 32 + quad * 8];
    #pragma unroll
    for (int nt = 0; nt < 4; ++nt) {
      bf16x8 bk = *(const bf16x8*)&Ks[(nt * 16 + l15) * 104 + k0 * 32 + quad * 8];
      accS[nt] = __builtin_amdgcn_mfma_f32_16x16x32_bf16(aq, bk, accS[nt], 0, 0, 0);
    }
  }

  // ---- softmax fully in-register: row r lives in the 16 lanes of one quad ----
  #pragma unroll
  for (int r = 0; r < 4; ++r) {
    int rg = wv * 16 + quad * 4 + r;          // global window-row (0..63)
    int yi = rg / 7, xi = rg - yi * 7;
    float sv[4];
    float mx = -3e38f;
    #pragma unroll
    for (int nt = 0; nt < 4; ++nt) {
      int col = nt * 16 + l15;
      float s = accS[nt][r] * scale;
      if (rg < 49 && col < 49) {
        int yj = col / 7, xj = col - yj * 7;
        s += rpb[((yi - yj + 6) * 13 + (xi - xj + 6)) * 6 + h];
      } else {
        s = -3e38f;                            // masks pad cols AND any NaN from pad LDS
      }
      sv[nt] = s;
      mx = fmaxf(mx, s);
    }
    #pragma unroll
    for (int off = 8; off; off >>= 1) mx = fmaxf(mx, __shfl_xor(mx, off));
    float sum = 0.f;
    #pragma unroll
    for (int nt = 0; nt < 4; ++nt) { sv[nt] = __expf(sv[nt] - mx); sum += sv[nt]; }
    #pragma unroll
    for (int off = 8; off; off >>= 1) sum += __shfl_xor(sum, off);
    float inv = 1.0f / sum;
    u16* psr = Ps + rg * 72;
    #pragma unroll
    for (int nt = 0; nt < 4; ++nt) psr[nt * 16 + l15] = f2bf(sv[nt] * inv);
  }
  __syncthreads();

  // ---- PV: O[i][d] = sum_j P[i][j] * Vt[d][j], K-dim = 64 (pad zeroed) ----
  f32x4 accO[6] = {};
  #pragma unroll
  for (int k0 = 0; k0 < 2; ++k0) {
    bf16x8 ap = *(const bf16x8*)&Ps[(wv * 16 + l15) * 72 + k0 * 32 + quad * 8];
    #pragma unroll
    for (int nt = 0; nt < 6; ++nt) {
      bf16x8 bv = *(const bf16x8*)&Vt[(nt * 16 + l15) * 72 + k0 * 32 + quad * 8];
      accO[nt] = __builtin_amdgcn_mfma_f32_16x16x32_bf16(ap, bv, accO[nt], 0, 0, 0);
    }
  }
  #pragma unroll
  for (int r = 0; r < 4; ++r) {
    int rg = wv * 16 + quad * 4 + r;
    if (rg < 49) {
      int tr = rg / 7, tc = rg - tr * 7;
      long ooff = ((long)b * 3136 + (wr * 7 + tr) * 56 + wc * 7 + tc) * 576 + h * 96;
      #pragma unroll
      for (int nt = 0; nt < 6; ++nt) obuf[ooff + nt * 16 + l15] = f2bf(accO[nt][r]);
    }
  }
}

// ---------------- bf16 MFMA GEMM: C(M,N) = A(M,K) @ Bt(N,K)^T + epi ------
// m97-style: tile 128x128x32, 256 threads (4 waves, 2x2), global_load_lds
// width-16 staging into linear LDS, 4x4 fragments/wave, 2 barriers/K-step.
// Requires M % 128 == 0 and K % 32 == 0 (true for all call sites).
// N remainder: B staging row clamped to N-1, stores guarded on col < N.
// EPI: 0 = +bias ; 1 = +bias, exact GELU ; 2 = +bias, +res
template <int EPI, typename TR, typename TO>
__global__ __launch_bounds__(256) void gemm_kernel(const u16* __restrict__ A,
                                                   const u16* __restrict__ Bt,
                                                   const float* __restrict__ bias,
                                                   const TR* __restrict__ res,
                                                   TO* __restrict__ C,
                                                   int M, int N, int K) {
  __shared__ __align__(16) u16 As[128 * 32];
  __shared__ __align__(16) u16 Bs[128 * 32];
  int n0 = blockIdx.x * 128;
  int m0 = blockIdx.y * 128;
  int tid = threadIdx.x;
  int lane = tid & 63, wv = tid >> 6;
  int quad = lane >> 4, l15 = lane & 15;
  int wr2 = wv >> 1, wc2 = wv & 1;            // wave -> 64x64 quadrant
  f32x4 acc[4][4] = {};

  // per-thread staging chunks (16B): chunk = it*256 + tid ; r = chunk>>2 ; kc = chunk&3
  int rA0 = tid >> 2, rA1 = (256 + tid) >> 2;
  int kc0 = (tid & 3) * 8, kc1 = kc0;          // (chunk&3) identical for it=0/1
  int rB0 = n0 + rA0; if (rB0 > N - 1) rB0 = N - 1;
  int rB1 = n0 + rA1; if (rB1 > N - 1) rB1 = N - 1;
  const u16* gA0 = A + (long)(m0 + rA0) * K + kc0;
  const u16* gA1 = A + (long)(m0 + rA1) * K + kc1;
  const u16* gB0 = Bt + (long)rB0 * K + kc0;
  const u16* gB1 = Bt + (long)rB1 * K + kc1;
  u16* lA0 = &As[(wv * 64) * 8];               // wave-uniform bases
  u16* lA1 = &As[(256 + wv * 64) * 8];
  u16* lB0 = &Bs[(wv * 64) * 8];
  u16* lB1 = &Bs[(256 + wv * 64) * 8];

  for (int k0 = 0; k0 < K; k0 += 32) {
    load_lds16(gA0 + k0, lA0);
    load_lds16(gA1 + k0, lA1);
    load_lds16(gB0 + k0, lB0);
    load_lds16(gB1 + k0, lB1);
    __syncthreads();                            // drains vmcnt -> tiles ready
    bf16x8 a[4], bfr[4];
    const u16* as = &As[(wr2 * 64 + l15) * 32 + quad * 8];
    const u16* bs = &Bs[(wc2 * 64 + l15) * 32 + quad * 8];
    #pragma unroll
    for (int mi = 0; mi < 4; ++mi) a[mi] = *(const bf16x8*)(as + mi * 512);
    #pragma unroll
    for (int ni = 0; ni < 4; ++ni) bfr[ni] = *(const bf16x8*)(bs + ni * 512);
    #pragma unroll
    for (int mi = 0; mi < 4; ++mi)
      #pragma unroll
      for (int ni = 0; ni < 4; ++ni)
        acc[mi][ni] = __builtin_amdgcn_mfma_f32_16x16x32_bf16(a[mi], bfr[ni], acc[mi][ni], 0, 0, 0);
    __syncthreads();                            // readers done before next stage
  }
  #pragma unroll
  for (int mi = 0; mi < 4; ++mi)
    #pragma unroll
    for (int ni = 0; ni < 4; ++ni) {
      int col = n0 + wc2 * 64 + ni * 16 + l15;
      if (col < N) {
        float bz = bias[col];
        #pragma unroll
        for (int r = 0; r < 4; ++r) {
          int row = m0 + wr2 * 64 + mi * 16 + quad * 4 + r;
          float v = acc[mi][ni][r] + bz;
          if (EPI == 1) v = 0.5f * v * (1.0f + erff(v * 0.70710678118654752f));
          if (EPI == 2) v += ldf(&res[(long)row * N + col]);
          long off = (long)row * N + col;
          if (sizeof(TO) == 2) ((u16*)C)[off] = f2bf(v);
          else                 ((float*)C)[off] = v;
        }
      }
    }
}

// ---------------- host launch -------------------------------------------
// Inputs fp32, OUTPUT FP32. ws peak ~93.8 MB.
// phase 1 (ln1/qkv/attn/proj) in 2 batch-halves, phase 2 in 4 batch-quarters.
extern "C" void kernel_launch(void* const* d_in, const int* in_sizes, int n_in,
                              void* d_out, int out_size, void* d_ws, size_t ws_size,
                              hipStream_t stream) {
  const float* x      = (const float*)d_in[0];
  const float* n1w    = (const float*)d_in[1];
  const float* n1b    = (const float*)d_in[2];
  const float* qkv_w  = (const float*)d_in[3];
  const float* qkv_b  = (const float*)d_in[4];
  const float* rpb    = (const float*)d_in[5];
  const float* proj_w = (const float*)d_in[6];
  const float* proj_b = (const float*)d_in[7];
  const float* n2w    = (const float*)d_in[8];
  const float* n2b    = (const float*)d_in[9];
  const float* fc1_w  = (const float*)d_in[10];
  const float* fc1_b  = (const float*)d_in[11];
  const float* fc2_w  = (const float*)d_in[12];
  const float* fc2_b  = (const float*)d_in[13];

  char* ws = (char*)d_ws;
  u16* wt_qkv  = (u16*)(ws + 0);           // 1728x576
  u16* wt_proj = (u16*)(ws + 1990656);     // 576x576
  u16* wt_fc1  = (u16*)(ws + 2654208);     // 1024x1600
  u16* wt_fc2  = (u16*)(ws + 5931008);     // 576x1024
  char* qkvpool = ws + 7110656;            // 43,352,064 B (12544x1728 bf16)
  char* lnpool  = ws + 50462720;           // 14,450,688 B (12544x576 bf16)
  u16* x1buf    = (u16*)(ws + 64913408);   // 25088x576 bf16 (end 93,814,784)

  transpose_kernel<<<3888, 256, 0, stream>>>(qkv_w, wt_qkv, 576, 1728);
  transpose_kernel<<<1296, 256, 0, stream>>>(proj_w, wt_proj, 576, 576);
  transpose_kernel<<<6400, 256, 0, stream>>>(fc1_w, wt_fc1, 1600, 1024);
  transpose_kernel<<<2304, 256, 0, stream>>>(fc2_w, wt_fc2, 1024, 576);

  // ---------- phase 1: two halves of 4 batches (12544 rows) ----------
  for (int h = 0; h < 2; ++h) {
    const long r0 = (long)h * 12544;
    u16* lnb  = (u16*)lnpool;          // ln1 out, then reused as attn out
    u16* qkvb = (u16*)qkvpool;
    ln_kernel<float><<<3136, 256, 0, stream>>>(x + r0 * 576, n1w, n1b, lnb);
    gemm_kernel<0, float, u16><<<dim3(14, 98), 256, 0, stream>>>(
        lnb, wt_qkv, qkv_b, (const float*)nullptr, qkvb, 12544, 1728, 576);
    attn_kernel<<<dim3(256, 6), 256, 0, stream>>>(qkvb, rpb, lnb);
    gemm_kernel<2, float, u16><<<dim3(5, 98), 256, 0, stream>>>(
        lnb, wt_proj, proj_b, x + r0 * 576, x1buf + r0 * 576, 12544, 576, 576);
  }

  // ---------- phase 2: four quarters of 2 batches (6272 rows) ----------
  for (int q = 0; q < 4; ++q) {
    const long r0 = (long)q * 6272;
    u16* ln2b  = (u16*)lnpool;                    //  7,225,344 B
    u16* colsb = (u16*)qkvpool;                   // 20,070,400 B
    u16* hb    = (u16*)(qkvpool + 20070400);      // 12,845,056 B
    ln_kernel<u16><<<1568, 256, 0, stream>>>(x1buf + r0 * 576, n2w, n2b, ln2b);
    gather_kernel<<<39200, 256, 0, stream>>>(ln2b, colsb);
    gemm_kernel<1, float, u16><<<dim3(8, 49), 256, 0, stream>>>(
        colsb, wt_fc1, fc1_b, (const float*)nullptr, hb, 6272, 1024, 1600);
    gemm_kernel<2, u16, float><<<dim3(5, 49), 256, 0, stream>>>(
        hb, wt_fc2, fc2_b, x1buf + r0 * 576, (float*)d_out + r0 * 576,
        6272, 576, 1024);
  }
}

// Round 3
// 767.398 us; speedup vs baseline: 1.3811x; 1.0702x over previous
//
#include <hip/hip_runtime.h>

typedef unsigned short u16;
typedef __bf16 bf16x8 __attribute__((ext_vector_type(8)));
typedef float f32x4 __attribute__((ext_vector_type(4)));

__device__ __forceinline__ float bf2f(u16 u) {
  union { unsigned int i; float f; } v; v.i = ((unsigned int)u) << 16; return v.f;
}
__device__ __forceinline__ u16 f2bf(float f) {
  union { float f; unsigned int i; } v; v.f = f;
  unsigned int i = v.i;
  return (u16)((i + 0x7fffu + ((i >> 16) & 1u)) >> 16);  // RNE
}
__device__ __forceinline__ float ldf(const float* p) { return *p; }
__device__ __forceinline__ float ldf(const u16* p) { return bf2f(*p); }

// async global->LDS, 16B per lane. LDS dest must be the wave-uniform base;
// HW writes base + lane*16 (guide §5: m97/m104).
__device__ __forceinline__ void load_lds16(const u16* g, u16* l) {
  __builtin_amdgcn_global_load_lds(
      (const __attribute__((address_space(1))) unsigned int*)g,
      (__attribute__((address_space(3))) unsigned int*)l, 16, 0, 0);
}

// ---------------- weight transpose + cast: Wt[n*K+k] = bf16(W[k*N+n]) ----
__global__ void transpose_kernel(const float* __restrict__ W, u16* __restrict__ Wt,
                                 int K, int N) {
  int idx = blockIdx.x * 256 + threadIdx.x;
  if (idx >= K * N) return;
  int k = idx / N, n = idx % N;
  Wt[n * K + k] = f2bf(W[idx]);
}

// ---------------- layernorm over C=576, 4 rows/block (1 wave each) -------
template <typename T>
__global__ __launch_bounds__(256) void ln_kernel(const T* __restrict__ x,
                                                 const float* __restrict__ w,
                                                 const float* __restrict__ b,
                                                 u16* __restrict__ out) {
  int wave = threadIdx.x >> 6, lane = threadIdx.x & 63;
  long row = (long)blockIdx.x * 4 + wave;
  const T* xr = x + row * 576;
  float v[9];
  float sum = 0.f;
  #pragma unroll
  for (int i = 0; i < 9; ++i) { v[i] = ldf(&xr[lane + i * 64]); sum += v[i]; }
  #pragma unroll
  for (int off = 32; off; off >>= 1) sum += __shfl_xor(sum, off);
  float mean = sum * (1.0f / 576.0f);
  float var = 0.f;
  #pragma unroll
  for (int i = 0; i < 9; ++i) { float d = v[i] - mean; var += d * d; }
  #pragma unroll
  for (int off = 32; off; off >>= 1) var += __shfl_xor(var, off);
  float rstd = rsqrtf(var * (1.0f / 576.0f) + 1e-5f);
  u16* outr = out + row * 576;
  #pragma unroll
  for (int i = 0; i < 9; ++i) {
    int c = lane + i * 64;
    outr[c] = f2bf((v[i] - mean) * rstd * w[c] + b[c]);
  }
}

// ---------------- DMlp gather: pixelshuffle(3) + reflpad(2) + masked unfold
// chunk-local: ln2 points at chunk start (whole batches), b chunk-relative.
__constant__ int c_di[25] = {0,0,0, 1,1,1, 2,2,2, 3,3,3,3,3,3,3, 4,4,4, 5,5,5, 6,6,6};
__constant__ int c_dj[25] = {0,3,6, 1,3,5, 2,3,4, 0,1,2,3,4,5,6, 2,3,4, 1,3,5, 0,3,6};

__device__ __forceinline__ int refl168(int t) {
  return t < 0 ? -t : (t >= 168 ? 334 - t : t);
}

__global__ __launch_bounds__(256) void gather_kernel(const u16* __restrict__ ln2,
                                                     u16* __restrict__ cols) {
  int idx = blockIdx.x * 256 + threadIdx.x;
  int f = idx % 1600;
  int n_ = idx / 1600;            // b*3136 + i*56 + j  (b chunk-relative)
  int bj = n_ % 3136, b = n_ / 3136;
  int i = bj / 56, j = bj % 56;
  int p = f % 25, nf = f / 25;
  int R  = refl168(c_di[p] + 3 * i - 2);
  int Cc = refl168(c_dj[p] + 3 * j - 2);
  int h2 = R / 3, a = R - 3 * h2;
  int w2 = Cc / 3, b2 = Cc - 3 * w2;
  long src = ((long)b * 3136 + h2 * 56 + w2) * 576 + nf * 9 + a * 3 + b2;
  cols[idx] = ln2[src];
}

// ---------------- window attention, MFMA version -------------------------
// one block per (window, head); 4 waves. QK^T and PV via mfma_f32_16x16x32_bf16
__global__ __launch_bounds__(256) void attn_kernel(const u16* __restrict__ qkv,
                                                   const float* __restrict__ rpb,
                                                   u16* __restrict__ obuf) {
  int h = blockIdx.y;            // 0..5
  int wi = blockIdx.x;
  int b = wi >> 6, w = wi & 63, wr = w >> 3, wc = w & 7;
  __shared__ __align__(16) u16 Qs[64 * 104];   // [t][d] stride 104 (16B-aligned rows)
  __shared__ __align__(16) u16 Ks[64 * 104];
  __shared__ __align__(16) u16 Vt[96 * 72];    // [d][t] transposed, cols 49..63 zeroed
  __shared__ __align__(16) u16 Ps[64 * 72];    // P bf16, [i][j], pad cols exactly 0
  int tid = threadIdx.x;
  int lane = tid & 63, wv = tid >> 6;
  int quad = lane >> 4, l15 = lane & 15;
  const float scale = 0.1020620726159658f;  // 96^-0.5

  long base = ((long)b * 3136 + wr * 7 * 56 + wc * 7) * 1728 + h * 96;

  // stage Q,K: coalesced uint4 (dq fastest), conflict-free b128 writes
  for (int idx = tid; idx < 588; idx += 256) {
    int t = idx / 12, dq = idx % 12;
    int tr = t / 7, tc = t - tr * 7;
    long roff = base + (tr * 56 + tc) * 1728 + dq * 8;
    *(uint4*)&Qs[t * 104 + dq * 8] = *(const uint4*)(qkv + roff);
    *(uint4*)&Ks[t * 104 + dq * 8] = *(const uint4*)(qkv + roff + 576);
  }
  // Vt pad cols (j = 49..63) must be 0: they multiply Ps pad cols (0) in MFMA
  for (int idx = tid; idx < 96 * 15; idx += 256) {
    int d = idx / 15, t = 49 + idx % 15;
    Vt[d * 72 + t] = 0;
  }
  // stage V transposed: t-fastest lane mapping -> conflict-free u16 LDS writes
  for (int idx = tid; idx < 768; idx += 256) {
    int dq = idx >> 6, t = idx & 63;
    if (t < 49) {
      int tr = t / 7, tc = t - tr * 7;
      uint4 v = *(const uint4*)(qkv + base + (tr * 56 + tc) * 1728 + 1152 + dq * 8);
      const u16* vv = (const u16*)&v;
      #pragma unroll
      for (int kk = 0; kk < 8; ++kk) Vt[(dq * 8 + kk) * 72 + t] = vv[kk];
    }
  }
  __syncthreads();

  // ---- QK^T: wave wv owns S rows [wv*16, wv*16+16) ----
  f32x4 accS[4] = {};
  #pragma unroll
  for (int k0 = 0; k0 < 3; ++k0) {
    bf16x8 aq = *(const bf16x8*)&Qs[(wv * 16 + l15) * 104 + k0 * 32 + quad * 8];
    #pragma unroll
    for (int nt = 0; nt < 4; ++nt) {
      bf16x8 bk = *(const bf16x8*)&Ks[(nt * 16 + l15) * 104 + k0 * 32 + quad * 8];
      accS[nt] = __builtin_amdgcn_mfma_f32_16x16x32_bf16(aq, bk, accS[nt], 0, 0, 0);
    }
  }

  // ---- softmax fully in-register: row r lives in the 16 lanes of one quad ----
  #pragma unroll
  for (int r = 0; r < 4; ++r) {
    int rg = wv * 16 + quad * 4 + r;          // global window-row (0..63)
    int yi = rg / 7, xi = rg - yi * 7;
    float sv[4];
    float mx = -3e38f;
    #pragma unroll
    for (int nt = 0; nt < 4; ++nt) {
      int col = nt * 16 + l15;
      float s = accS[nt][r] * scale;
      if (rg < 49 && col < 49) {
        int yj = col / 7, xj = col - yj * 7;
        s += rpb[((yi - yj + 6) * 13 + (xi - xj + 6)) * 6 + h];
      } else {
        s = -3e38f;                            // masks pad cols AND any NaN from pad LDS
      }
      sv[nt] = s;
      mx = fmaxf(mx, s);
    }
    #pragma unroll
    for (int off = 8; off; off >>= 1) mx = fmaxf(mx, __shfl_xor(mx, off));
    float sum = 0.f;
    #pragma unroll
    for (int nt = 0; nt < 4; ++nt) { sv[nt] = __expf(sv[nt] - mx); sum += sv[nt]; }
    #pragma unroll
    for (int off = 8; off; off >>= 1) sum += __shfl_xor(sum, off);
    float inv = 1.0f / sum;
    u16* psr = Ps + rg * 72;
    #pragma unroll
    for (int nt = 0; nt < 4; ++nt) psr[nt * 16 + l15] = f2bf(sv[nt] * inv);
  }
  __syncthreads();

  // ---- PV: O[i][d] = sum_j P[i][j] * Vt[d][j], K-dim = 64 (pad zeroed) ----
  f32x4 accO[6] = {};
  #pragma unroll
  for (int k0 = 0; k0 < 2; ++k0) {
    bf16x8 ap = *(const bf16x8*)&Ps[(wv * 16 + l15) * 72 + k0 * 32 + quad * 8];
    #pragma unroll
    for (int nt = 0; nt < 6; ++nt) {
      bf16x8 bv = *(const bf16x8*)&Vt[(nt * 16 + l15) * 72 + k0 * 32 + quad * 8];
      accO[nt] = __builtin_amdgcn_mfma_f32_16x16x32_bf16(ap, bv, accO[nt], 0, 0, 0);
    }
  }
  #pragma unroll
  for (int r = 0; r < 4; ++r) {
    int rg = wv * 16 + quad * 4 + r;
    if (rg < 49) {
      int tr = rg / 7, tc = rg - tr * 7;
      long ooff = ((long)b * 3136 + (wr * 7 + tr) * 56 + wc * 7 + tc) * 576 + h * 96;
      #pragma unroll
      for (int nt = 0; nt < 6; ++nt) obuf[ooff + nt * 16 + l15] = f2bf(accO[nt][r]);
    }
  }
}

// ---------------- bf16 MFMA GEMM: C(M,N) = A(M,K) @ Bt(N,K)^T + epi ------
// m97-style: tile 128x128x32, 256 threads (4 waves, 2x2), global_load_lds
// width-16 staging into linear LDS, 4x4 fragments/wave, 2 barriers/K-step.
// Requires M % 128 == 0 and K % 32 == 0 (true for all call sites).
// N remainder: B staging row clamped to N-1, stores guarded on col < N.
// EPI: 0 = +bias ; 1 = +bias, exact GELU ; 2 = +bias, +res
template <int EPI, typename TR, typename TO>
__global__ __launch_bounds__(256) void gemm_kernel(const u16* __restrict__ A,
                                                   const u16* __restrict__ Bt,
                                                   const float* __restrict__ bias,
                                                   const TR* __restrict__ res,
                                                   TO* __restrict__ C,
                                                   int M, int N, int K) {
  __shared__ __align__(16) u16 As[128 * 32];
  __shared__ __align__(16) u16 Bs[128 * 32];
  int n0 = blockIdx.x * 128;
  int m0 = blockIdx.y * 128;
  int tid = threadIdx.x;
  int lane = tid & 63, wv = tid >> 6;
  int quad = lane >> 4, l15 = lane & 15;
  int wr2 = wv >> 1, wc2 = wv & 1;            // wave -> 64x64 quadrant
  f32x4 acc[4][4] = {};

  // per-thread staging chunks (16B): chunk = it*256 + tid ; r = chunk>>2 ; kc = chunk&3
  int rA0 = tid >> 2, rA1 = (256 + tid) >> 2;
  int kc0 = (tid & 3) * 8, kc1 = kc0;          // (chunk&3) identical for it=0/1
  int rB0 = n0 + rA0; if (rB0 > N - 1) rB0 = N - 1;
  int rB1 = n0 + rA1; if (rB1 > N - 1) rB1 = N - 1;
  const u16* gA0 = A + (long)(m0 + rA0) * K + kc0;
  const u16* gA1 = A + (long)(m0 + rA1) * K + kc1;
  const u16* gB0 = Bt + (long)rB0 * K + kc0;
  const u16* gB1 = Bt + (long)rB1 * K + kc1;
  u16* lA0 = &As[(wv * 64) * 8];               // wave-uniform bases
  u16* lA1 = &As[(256 + wv * 64) * 8];
  u16* lB0 = &Bs[(wv * 64) * 8];
  u16* lB1 = &Bs[(256 + wv * 64) * 8];

  for (int k0 = 0; k0 < K; k0 += 32) {
    load_lds16(gA0 + k0, lA0);
    load_lds16(gA1 + k0, lA1);
    load_lds16(gB0 + k0, lB0);
    load_lds16(gB1 + k0, lB1);
    __syncthreads();                            // drains vmcnt -> tiles ready
    bf16x8 a[4], bfr[4];
    const u16* as = &As[(wr2 * 64 + l15) * 32 + quad * 8];
    const u16* bs = &Bs[(wc2 * 64 + l15) * 32 + quad * 8];
    #pragma unroll
    for (int mi = 0; mi < 4; ++mi) a[mi] = *(const bf16x8*)(as + mi * 512);
    #pragma unroll
    for (int ni = 0; ni < 4; ++ni) bfr[ni] = *(const bf16x8*)(bs + ni * 512);
    #pragma unroll
    for (int mi = 0; mi < 4; ++mi)
      #pragma unroll
      for (int ni = 0; ni < 4; ++ni)
        acc[mi][ni] = __builtin_amdgcn_mfma_f32_16x16x32_bf16(a[mi], bfr[ni], acc[mi][ni], 0, 0, 0);
    __syncthreads();                            // readers done before next stage
  }
  #pragma unroll
  for (int mi = 0; mi < 4; ++mi)
    #pragma unroll
    for (int ni = 0; ni < 4; ++ni) {
      int col = n0 + wc2 * 64 + ni * 16 + l15;
      if (col < N) {
        float bz = bias[col];
        #pragma unroll
        for (int r = 0; r < 4; ++r) {
          int row = m0 + wr2 * 64 + mi * 16 + quad * 4 + r;
          float v = acc[mi][ni][r] + bz;
          if (EPI == 1) v = 0.5f * v * (1.0f + erff(v * 0.70710678118654752f));
          if (EPI == 2) v += ldf(&res[(long)row * N + col]);
          long off = (long)row * N + col;
          if (sizeof(TO) == 2) ((u16*)C)[off] = f2bf(v);
          else                 ((float*)C)[off] = v;
        }
      }
    }
}

// ---------------- host launch -------------------------------------------
// Inputs fp32, OUTPUT FP32. ws peak ~90.6 MB.
// x1 (phase-1 output) lives in d_out as f32: proj writes it, phase-2 LN
// reads it, fc2 reads it as residual and overwrites in place (each element
// touched exactly once, read-before-write in the same thread; phase 1 fully
// rewrites d_out before phase 2 reads -> graph-replay idempotent).
extern "C" void kernel_launch(void* const* d_in, const int* in_sizes, int n_in,
                              void* d_out, int out_size, void* d_ws, size_t ws_size,
                              hipStream_t stream) {
  const float* x      = (const float*)d_in[0];
  const float* n1w    = (const float*)d_in[1];
  const float* n1b    = (const float*)d_in[2];
  const float* qkv_w  = (const float*)d_in[3];
  const float* qkv_b  = (const float*)d_in[4];
  const float* rpb    = (const float*)d_in[5];
  const float* proj_w = (const float*)d_in[6];
  const float* proj_b = (const float*)d_in[7];
  const float* n2w    = (const float*)d_in[8];
  const float* n2b    = (const float*)d_in[9];
  const float* fc1_w  = (const float*)d_in[10];
  const float* fc1_b  = (const float*)d_in[11];
  const float* fc2_w  = (const float*)d_in[12];
  const float* fc2_b  = (const float*)d_in[13];

  char* ws = (char*)d_ws;
  u16* wt_qkv  = (u16*)(ws + 0);           // 1728x576
  u16* wt_proj = (u16*)(ws + 1990656);     // 576x576
  u16* wt_fc1  = (u16*)(ws + 2654208);     // 1024x1600
  u16* wt_fc2  = (u16*)(ws + 5931008);     // 576x1024
  char* qkvpool = ws + 7110656;            // 43,352,064 B (ph1 qkvb / ph2 colsb)
  char* lnpool  = ws + 50462720;           // 14,450,688 B (ph1 lnb / ph2 ln2b)
  char* hpool   = ws + 64913408;           // 25,690,112 B (ph2 hb) end 90,603,520
  float* x1 = (float*)d_out;               // 25088x576 f32

  transpose_kernel<<<3888, 256, 0, stream>>>(qkv_w, wt_qkv, 576, 1728);
  transpose_kernel<<<1296, 256, 0, stream>>>(proj_w, wt_proj, 576, 576);
  transpose_kernel<<<6400, 256, 0, stream>>>(fc1_w, wt_fc1, 1600, 1024);
  transpose_kernel<<<2304, 256, 0, stream>>>(fc2_w, wt_fc2, 1024, 576);

  // ---------- phase 1: two halves of 4 batches (12544 rows each) ----------
  for (int h = 0; h < 2; ++h) {
    const long r0 = (long)h * 12544;
    u16* lnb  = (u16*)lnpool;          // ln1 out, then reused as attn out
    u16* qkvb = (u16*)qkvpool;
    ln_kernel<float><<<3136, 256, 0, stream>>>(x + r0 * 576, n1w, n1b, lnb);
    gemm_kernel<0, float, u16><<<dim3(14, 98), 256, 0, stream>>>(
        lnb, wt_qkv, qkv_b, (const float*)nullptr, qkvb, 12544, 1728, 576);
    attn_kernel<<<dim3(256, 6), 256, 0, stream>>>(qkvb, rpb, lnb);
    gemm_kernel<2, float, float><<<dim3(5, 98), 256, 0, stream>>>(
        lnb, wt_proj, proj_b, x + r0 * 576, x1 + r0 * 576, 12544, 576, 576);
  }

  // ---------- phase 2: two halves of 4 batches (12544 rows each) ----------
  for (int q = 0; q < 2; ++q) {
    const long r0 = (long)q * 12544;
    u16* ln2b  = (u16*)lnpool;                    // 14,450,688 B
    u16* colsb = (u16*)qkvpool;                   // 40,140,800 B
    u16* hb    = (u16*)hpool;                     // 25,690,112 B
    ln_kernel<float><<<3136, 256, 0, stream>>>(x1 + r0 * 576, n2w, n2b, ln2b);
    gather_kernel<<<78400, 256, 0, stream>>>(ln2b, colsb);
    gemm_kernel<1, float, u16><<<dim3(8, 98), 256, 0, stream>>>(
        colsb, wt_fc1, fc1_b, (const float*)nullptr, hb, 12544, 1024, 1600);
    gemm_kernel<2, float, float><<<dim3(5, 98), 256, 0, stream>>>(
        hb, wt_fc2, fc2_b, x1 + r0 * 576, x1 + r0 * 576, 12544, 576, 1024);
  }
}

// Round 4
// 737.160 us; speedup vs baseline: 1.4378x; 1.0410x over previous
//
#include <hip/hip_runtime.h>

typedef unsigned short u16;
typedef __bf16 bf16x8 __attribute__((ext_vector_type(8)));
typedef float f32x4 __attribute__((ext_vector_type(4)));

__device__ __forceinline__ float bf2f(u16 u) {
  union { unsigned int i; float f; } v; v.i = ((unsigned int)u) << 16; return v.f;
}
__device__ __forceinline__ u16 f2bf(float f) {
  union { float f; unsigned int i; } v; v.f = f;
  unsigned int i = v.i;
  return (u16)((i + 0x7fffu + ((i >> 16) & 1u)) >> 16);  // RNE
}
__device__ __forceinline__ float ldf(const float* p) { return *p; }
__device__ __forceinline__ float ldf(const u16* p) { return bf2f(*p); }

// async global->LDS, 16B per lane. LDS dest must be the wave-uniform base;
// HW writes base + lane*16 (guide §5: m97/m104).
__device__ __forceinline__ void load_lds16(const u16* g, u16* l) {
  __builtin_amdgcn_global_load_lds(
      (const __attribute__((address_space(1))) unsigned int*)g,
      (__attribute__((address_space(3))) unsigned int*)l, 16, 0, 0);
}

// ---------------- weight transpose + cast: Wt[n*K+k] = bf16(W[k*N+n]) ----
__global__ void transpose_kernel(const float* __restrict__ W, u16* __restrict__ Wt,
                                 int K, int N) {
  int idx = blockIdx.x * 256 + threadIdx.x;
  if (idx >= K * N) return;
  int k = idx / N, n = idx % N;
  Wt[n * K + k] = f2bf(W[idx]);
}

// ---------------- layernorm over C=576, 4 rows/block (1 wave each) -------
template <typename T>
__global__ __launch_bounds__(256) void ln_kernel(const T* __restrict__ x,
                                                 const float* __restrict__ w,
                                                 const float* __restrict__ b,
                                                 u16* __restrict__ out) {
  int wave = threadIdx.x >> 6, lane = threadIdx.x & 63;
  long row = (long)blockIdx.x * 4 + wave;
  const T* xr = x + row * 576;
  float v[9];
  float sum = 0.f;
  #pragma unroll
  for (int i = 0; i < 9; ++i) { v[i] = ldf(&xr[lane + i * 64]); sum += v[i]; }
  #pragma unroll
  for (int off = 32; off; off >>= 1) sum += __shfl_xor(sum, off);
  float mean = sum * (1.0f / 576.0f);
  float var = 0.f;
  #pragma unroll
  for (int i = 0; i < 9; ++i) { float d = v[i] - mean; var += d * d; }
  #pragma unroll
  for (int off = 32; off; off >>= 1) var += __shfl_xor(var, off);
  float rstd = rsqrtf(var * (1.0f / 576.0f) + 1e-5f);
  u16* outr = out + row * 576;
  #pragma unroll
  for (int i = 0; i < 9; ++i) {
    int c = lane + i * 64;
    outr[c] = f2bf((v[i] - mean) * rstd * w[c] + b[c]);
  }
}

// ---------------- DMlp gather: pixelshuffle(3) + reflpad(2) + masked unfold
// chunk-local: ln2 points at chunk start (whole batches), b chunk-relative.
__constant__ int c_di[25] = {0,0,0, 1,1,1, 2,2,2, 3,3,3,3,3,3,3, 4,4,4, 5,5,5, 6,6,6};
__constant__ int c_dj[25] = {0,3,6, 1,3,5, 2,3,4, 0,1,2,3,4,5,6, 2,3,4, 1,3,5, 0,3,6};

__device__ __forceinline__ int refl168(int t) {
  return t < 0 ? -t : (t >= 168 ? 334 - t : t);
}

__global__ __launch_bounds__(256) void gather_kernel(const u16* __restrict__ ln2,
                                                     u16* __restrict__ cols) {
  int idx = blockIdx.x * 256 + threadIdx.x;
  int f = idx % 1600;
  int n_ = idx / 1600;            // b*3136 + i*56 + j  (b chunk-relative)
  int bj = n_ % 3136, b = n_ / 3136;
  int i = bj / 56, j = bj % 56;
  int p = f % 25, nf = f / 25;
  int R  = refl168(c_di[p] + 3 * i - 2);
  int Cc = refl168(c_dj[p] + 3 * j - 2);
  int h2 = R / 3, a = R - 3 * h2;
  int w2 = Cc / 3, b2 = Cc - 3 * w2;
  long src = ((long)b * 3136 + h2 * 56 + w2) * 576 + nf * 9 + a * 3 + b2;
  cols[idx] = ln2[src];
}

// ---------------- window attention, MFMA version -------------------------
// one block per (window, head); 4 waves. QK^T and PV via mfma_f32_16x16x32_bf16
__global__ __launch_bounds__(256) void attn_kernel(const u16* __restrict__ qkv,
                                                   const float* __restrict__ rpb,
                                                   u16* __restrict__ obuf) {
  int h = blockIdx.y;            // 0..5
  int wi = blockIdx.x;
  int b = wi >> 6, w = wi & 63, wr = w >> 3, wc = w & 7;
  __shared__ __align__(16) u16 Qs[64 * 104];   // [t][d] stride 104 (16B-aligned rows)
  __shared__ __align__(16) u16 Ks[64 * 104];
  __shared__ __align__(16) u16 Vt[96 * 72];    // [d][t] transposed, cols 49..63 zeroed
  __shared__ __align__(16) u16 Ps[64 * 72];    // P bf16, [i][j], pad cols exactly 0
  int tid = threadIdx.x;
  int lane = tid & 63, wv = tid >> 6;
  int quad = lane >> 4, l15 = lane & 15;
  const float scale = 0.1020620726159658f;  // 96^-0.5

  long base = ((long)b * 3136 + wr * 7 * 56 + wc * 7) * 1728 + h * 96;

  // stage Q,K: coalesced uint4 (dq fastest), conflict-free b128 writes
  for (int idx = tid; idx < 588; idx += 256) {
    int t = idx / 12, dq = idx % 12;
    int tr = t / 7, tc = t - tr * 7;
    long roff = base + (tr * 56 + tc) * 1728 + dq * 8;
    *(uint4*)&Qs[t * 104 + dq * 8] = *(const uint4*)(qkv + roff);
    *(uint4*)&Ks[t * 104 + dq * 8] = *(const uint4*)(qkv + roff + 576);
  }
  // Vt pad cols (j = 49..63) must be 0: they multiply Ps pad cols (0) in MFMA
  for (int idx = tid; idx < 96 * 15; idx += 256) {
    int d = idx / 15, t = 49 + idx % 15;
    Vt[d * 72 + t] = 0;
  }
  // stage V transposed: t-fastest lane mapping -> conflict-free u16 LDS writes
  for (int idx = tid; idx < 768; idx += 256) {
    int dq = idx >> 6, t = idx & 63;
    if (t < 49) {
      int tr = t / 7, tc = t - tr * 7;
      uint4 v = *(const uint4*)(qkv + base + (tr * 56 + tc) * 1728 + 1152 + dq * 8);
      const u16* vv = (const u16*)&v;
      #pragma unroll
      for (int kk = 0; kk < 8; ++kk) Vt[(dq * 8 + kk) * 72 + t] = vv[kk];
    }
  }
  __syncthreads();

  // ---- QK^T: wave wv owns S rows [wv*16, wv*16+16) ----
  f32x4 accS[4] = {};
  #pragma unroll
  for (int k0 = 0; k0 < 3; ++k0) {
    bf16x8 aq = *(const bf16x8*)&Qs[(wv * 16 + l15) * 104 + k0 * 32 + quad * 8];
    #pragma unroll
    for (int nt = 0; nt < 4; ++nt) {
      bf16x8 bk = *(const bf16x8*)&Ks[(nt * 16 + l15) * 104 + k0 * 32 + quad * 8];
      accS[nt] = __builtin_amdgcn_mfma_f32_16x16x32_bf16(aq, bk, accS[nt], 0, 0, 0);
    }
  }

  // ---- softmax fully in-register: row r lives in the 16 lanes of one quad ----
  #pragma unroll
  for (int r = 0; r < 4; ++r) {
    int rg = wv * 16 + quad * 4 + r;          // global window-row (0..63)
    int yi = rg / 7, xi = rg - yi * 7;
    float sv[4];
    float mx = -3e38f;
    #pragma unroll
    for (int nt = 0; nt < 4; ++nt) {
      int col = nt * 16 + l15;
      float s = accS[nt][r] * scale;
      if (rg < 49 && col < 49) {
        int yj = col / 7, xj = col - yj * 7;
        s += rpb[((yi - yj + 6) * 13 + (xi - xj + 6)) * 6 + h];
      } else {
        s = -3e38f;                            // masks pad cols AND any NaN from pad LDS
      }
      sv[nt] = s;
      mx = fmaxf(mx, s);
    }
    #pragma unroll
    for (int off = 8; off; off >>= 1) mx = fmaxf(mx, __shfl_xor(mx, off));
    float sum = 0.f;
    #pragma unroll
    for (int nt = 0; nt < 4; ++nt) { sv[nt] = __expf(sv[nt] - mx); sum += sv[nt]; }
    #pragma unroll
    for (int off = 8; off; off >>= 1) sum += __shfl_xor(sum, off);
    float inv = 1.0f / sum;
    u16* psr = Ps + rg * 72;
    #pragma unroll
    for (int nt = 0; nt < 4; ++nt) psr[nt * 16 + l15] = f2bf(sv[nt] * inv);
  }
  __syncthreads();

  // ---- PV: O[i][d] = sum_j P[i][j] * Vt[d][j], K-dim = 64 (pad zeroed) ----
  f32x4 accO[6] = {};
  #pragma unroll
  for (int k0 = 0; k0 < 2; ++k0) {
    bf16x8 ap = *(const bf16x8*)&Ps[(wv * 16 + l15) * 72 + k0 * 32 + quad * 8];
    #pragma unroll
    for (int nt = 0; nt < 6; ++nt) {
      bf16x8 bv = *(const bf16x8*)&Vt[(nt * 16 + l15) * 72 + k0 * 32 + quad * 8];
      accO[nt] = __builtin_amdgcn_mfma_f32_16x16x32_bf16(ap, bv, accO[nt], 0, 0, 0);
    }
  }
  #pragma unroll
  for (int r = 0; r < 4; ++r) {
    int rg = wv * 16 + quad * 4 + r;
    if (rg < 49) {
      int tr = rg / 7, tc = rg - tr * 7;
      long ooff = ((long)b * 3136 + (wr * 7 + tr) * 56 + wc * 7 + tc) * 576 + h * 96;
      #pragma unroll
      for (int nt = 0; nt < 6; ++nt) obuf[ooff + nt * 16 + l15] = f2bf(accO[nt][r]);
    }
  }
}

// ---------------- bf16 MFMA GEMM: C(M,N) = A(M,K) @ Bt(N,K)^T + epi ------
// tile 128x128x32, 256 threads (4 waves, 2x2), global_load_lds width-16
// staging, double-buffered LDS, counted-vmcnt prefetch (T3/T4-lite), raw
// s_barrier, XCD-chunked bijective block swizzle (T1/m204).
// Requires M % 128 == 0 and K % 32 == 0 (true for all call sites).
// N remainder: B staging row clamped to N-1, stores guarded on col < N.
// EPI: 0 = +bias ; 1 = +bias, exact GELU ; 2 = +bias, +res
template <int EPI, typename TR, typename TO>
__global__ __launch_bounds__(256) void gemm_kernel(const u16* __restrict__ A,
                                                   const u16* __restrict__ Bt,
                                                   const float* __restrict__ bias,
                                                   const TR* __restrict__ res,
                                                   TO* __restrict__ C,
                                                   int M, int N, int K) {
  __shared__ __align__(16) u16 As[2][128 * 32];
  __shared__ __align__(16) u16 Bs[2][128 * 32];

  // XCD-chunked bijective swizzle: HW assigns xcd = flat % 8 round-robin;
  // remap so each XCD owns a contiguous range of the logical (n-fastest)
  // grid -> all N-blocks of an M-panel share one XCD's L2 (A-panel reuse).
  int nwg = gridDim.x * gridDim.y;
  int flat = blockIdx.y * gridDim.x + blockIdx.x;
  int q = nwg >> 3, r = nwg & 7;
  int xcd = flat & 7, loc = flat >> 3;
  int newflat = ((xcd < r) ? xcd * (q + 1) : r * (q + 1) + (xcd - r) * q) + loc;
  int nblk = newflat % gridDim.x, mblk = newflat / gridDim.x;
  int n0 = nblk * 128;
  int m0 = mblk * 128;

  int tid = threadIdx.x;
  int lane = tid & 63, wv = tid >> 6;
  int quad = lane >> 4, l15 = lane & 15;
  int wr2 = wv >> 1, wc2 = wv & 1;            // wave -> 64x64 quadrant
  f32x4 acc[4][4] = {};

  // per-thread staging chunks (16B): chunk = it*256 + tid ; r = chunk>>2 ; kc = chunk&3
  int rA0 = tid >> 2, rA1 = (256 + tid) >> 2;
  int kc0 = (tid & 3) * 8;
  int rB0 = n0 + rA0; if (rB0 > N - 1) rB0 = N - 1;
  int rB1 = n0 + rA1; if (rB1 > N - 1) rB1 = N - 1;
  const u16* gA0 = A + (long)(m0 + rA0) * K + kc0;
  const u16* gA1 = A + (long)(m0 + rA1) * K + kc0;
  const u16* gB0 = Bt + (long)rB0 * K + kc0;
  const u16* gB1 = Bt + (long)rB1 * K + kc0;
  int lo0 = (wv * 64) * 8, lo1 = (256 + wv * 64) * 8;  // wave-uniform LDS bases

  int nt = K >> 5;
  #define STAGE(bufi, kk) do {                    \
    load_lds16(gA0 + (kk), &As[bufi][lo0]);       \
    load_lds16(gA1 + (kk), &As[bufi][lo1]);       \
    load_lds16(gB0 + (kk), &Bs[bufi][lo0]);       \
    load_lds16(gB1 + (kk), &Bs[bufi][lo1]); } while (0)

  auto compute = [&](int cur) {
    bf16x8 a[4], bfr[4];
    const u16* as = &As[cur][(wr2 * 64 + l15) * 32 + quad * 8];
    const u16* bs = &Bs[cur][(wc2 * 64 + l15) * 32 + quad * 8];
    #pragma unroll
    for (int mi = 0; mi < 4; ++mi) a[mi] = *(const bf16x8*)(as + mi * 512);
    #pragma unroll
    for (int ni = 0; ni < 4; ++ni) bfr[ni] = *(const bf16x8*)(bs + ni * 512);
    #pragma unroll
    for (int mi = 0; mi < 4; ++mi)
      #pragma unroll
      for (int ni = 0; ni < 4; ++ni)
        acc[mi][ni] = __builtin_amdgcn_mfma_f32_16x16x32_bf16(a[mi], bfr[ni], acc[mi][ni], 0, 0, 0);
  };

  STAGE(0, 0);
  for (int t = 0; t < nt - 1; ++t) {
    int cur = t & 1;
    STAGE(cur ^ 1, (t + 1) * 32);                 // prefetch next tile
    asm volatile("s_waitcnt vmcnt(4)" ::: "memory");  // own tile-t loads done
    __builtin_amdgcn_s_barrier();                 // all waves' tile-t loads done
    compute(cur);
    __builtin_amdgcn_s_barrier();                 // all readers of buf[cur] done
  }
  asm volatile("s_waitcnt vmcnt(0)" ::: "memory");
  __builtin_amdgcn_s_barrier();
  compute((nt - 1) & 1);
  #undef STAGE

  #pragma unroll
  for (int mi = 0; mi < 4; ++mi)
    #pragma unroll
    for (int ni = 0; ni < 4; ++ni) {
      int col = n0 + wc2 * 64 + ni * 16 + l15;
      if (col < N) {
        float bz = bias[col];
        #pragma unroll
        for (int rr = 0; rr < 4; ++rr) {
          int row = m0 + wr2 * 64 + mi * 16 + quad * 4 + rr;
          float v = acc[mi][ni][rr] + bz;
          if (EPI == 1) v = 0.5f * v * (1.0f + erff(v * 0.70710678118654752f));
          if (EPI == 2) v += ldf(&res[(long)row * N + col]);
          long off = (long)row * N + col;
          if (sizeof(TO) == 2) ((u16*)C)[off] = f2bf(v);
          else                 ((float*)C)[off] = v;
        }
      }
    }
}

// ---------------- host launch -------------------------------------------
// Inputs fp32, OUTPUT FP32. ws peak ~90.6 MB.
// x1 (phase-1 output) lives in d_out as f32: proj writes it, phase-2 LN
// reads it, fc2 reads it as residual and overwrites in place (each element
// touched exactly once, read-before-write in the same thread; phase 1 fully
// rewrites d_out before phase 2 reads -> graph-replay idempotent).
extern "C" void kernel_launch(void* const* d_in, const int* in_sizes, int n_in,
                              void* d_out, int out_size, void* d_ws, size_t ws_size,
                              hipStream_t stream) {
  const float* x      = (const float*)d_in[0];
  const float* n1w    = (const float*)d_in[1];
  const float* n1b    = (const float*)d_in[2];
  const float* qkv_w  = (const float*)d_in[3];
  const float* qkv_b  = (const float*)d_in[4];
  const float* rpb    = (const float*)d_in[5];
  const float* proj_w = (const float*)d_in[6];
  const float* proj_b = (const float*)d_in[7];
  const float* n2w    = (const float*)d_in[8];
  const float* n2b    = (const float*)d_in[9];
  const float* fc1_w  = (const float*)d_in[10];
  const float* fc1_b  = (const float*)d_in[11];
  const float* fc2_w  = (const float*)d_in[12];
  const float* fc2_b  = (const float*)d_in[13];

  char* ws = (char*)d_ws;
  u16* wt_qkv  = (u16*)(ws + 0);           // 1728x576
  u16* wt_proj = (u16*)(ws + 1990656);     // 576x576
  u16* wt_fc1  = (u16*)(ws + 2654208);     // 1024x1600
  u16* wt_fc2  = (u16*)(ws + 5931008);     // 576x1024
  char* qkvpool = ws + 7110656;            // 43,352,064 B (ph1 qkvb / ph2 colsb)
  char* lnpool  = ws + 50462720;           // 14,450,688 B (ph1 lnb / ph2 ln2b)
  char* hpool   = ws + 64913408;           // 25,690,112 B (ph2 hb) end 90,603,520
  float* x1 = (float*)d_out;               // 25088x576 f32

  transpose_kernel<<<3888, 256, 0, stream>>>(qkv_w, wt_qkv, 576, 1728);
  transpose_kernel<<<1296, 256, 0, stream>>>(proj_w, wt_proj, 576, 576);
  transpose_kernel<<<6400, 256, 0, stream>>>(fc1_w, wt_fc1, 1600, 1024);
  transpose_kernel<<<2304, 256, 0, stream>>>(fc2_w, wt_fc2, 1024, 576);

  // ---------- phase 1: two halves of 4 batches (12544 rows each) ----------
  for (int h = 0; h < 2; ++h) {
    const long r0 = (long)h * 12544;
    u16* lnb  = (u16*)lnpool;          // ln1 out, then reused as attn out
    u16* qkvb = (u16*)qkvpool;
    ln_kernel<float><<<3136, 256, 0, stream>>>(x + r0 * 576, n1w, n1b, lnb);
    gemm_kernel<0, float, u16><<<dim3(14, 98), 256, 0, stream>>>(
        lnb, wt_qkv, qkv_b, (const float*)nullptr, qkvb, 12544, 1728, 576);
    attn_kernel<<<dim3(256, 6), 256, 0, stream>>>(qkvb, rpb, lnb);
    gemm_kernel<2, float, float><<<dim3(5, 98), 256, 0, stream>>>(
        lnb, wt_proj, proj_b, x + r0 * 576, x1 + r0 * 576, 12544, 576, 576);
  }

  // ---------- phase 2: two halves of 4 batches (12544 rows each) ----------
  for (int q = 0; q < 2; ++q) {
    const long r0 = (long)q * 12544;
    u16* ln2b  = (u16*)lnpool;                    // 14,450,688 B
    u16* colsb = (u16*)qkvpool;                   // 40,140,800 B
    u16* hb    = (u16*)hpool;                     // 25,690,112 B
    ln_kernel<float><<<3136, 256, 0, stream>>>(x1 + r0 * 576, n2w, n2b, ln2b);
    gather_kernel<<<78400, 256, 0, stream>>>(ln2b, colsb);
    gemm_kernel<1, float, u16><<<dim3(8, 98), 256, 0, stream>>>(
        colsb, wt_fc1, fc1_b, (const float*)nullptr, hb, 12544, 1024, 1600);
    gemm_kernel<2, float, float><<<dim3(5, 98), 256, 0, stream>>>(
        hb, wt_fc2, fc2_b, x1 + r0 * 576, x1 + r0 * 576, 12544, 576, 1024);
  }
}

// Round 5
// 705.843 us; speedup vs baseline: 1.5016x; 1.0444x over previous
//
#include <hip/hip_runtime.h>

typedef unsigned short u16;
typedef __bf16 bf16x8 __attribute__((ext_vector_type(8)));
typedef float f32x4 __attribute__((ext_vector_type(4)));

__device__ __forceinline__ float bf2f(u16 u) {
  union { unsigned int i; float f; } v; v.i = ((unsigned int)u) << 16; return v.f;
}
__device__ __forceinline__ u16 f2bf(float f) {
  union { float f; unsigned int i; } v; v.f = f;
  unsigned int i = v.i;
  return (u16)((i + 0x7fffu + ((i >> 16) & 1u)) >> 16);  // RNE
}
__device__ __forceinline__ float ldf(const float* p) { return *p; }
__device__ __forceinline__ float ldf(const u16* p) { return bf2f(*p); }

// async global->LDS, 16B per lane. LDS dest must be the wave-uniform base;
// HW writes base + lane*16 (guide §5: m97/m104).
__device__ __forceinline__ void load_lds16(const u16* g, u16* l) {
  __builtin_amdgcn_global_load_lds(
      (const __attribute__((address_space(1))) unsigned int*)g,
      (__attribute__((address_space(3))) unsigned int*)l, 16, 0, 0);
}

// ---------------- weight transpose + cast: Wt[n*K+k] = bf16(W[k*N+n]) ----
__global__ void transpose_kernel(const float* __restrict__ W, u16* __restrict__ Wt,
                                 int K, int N) {
  int idx = blockIdx.x * 256 + threadIdx.x;
  if (idx >= K * N) return;
  int k = idx / N, n = idx % N;
  Wt[n * K + k] = f2bf(W[idx]);
}

// ---------------- layernorm over C=576, 4 rows/block (1 wave each) -------
template <typename T>
__global__ __launch_bounds__(256) void ln_kernel(const T* __restrict__ x,
                                                 const float* __restrict__ w,
                                                 const float* __restrict__ b,
                                                 u16* __restrict__ out) {
  int wave = threadIdx.x >> 6, lane = threadIdx.x & 63;
  long row = (long)blockIdx.x * 4 + wave;
  const T* xr = x + row * 576;
  float v[9];
  float sum = 0.f;
  #pragma unroll
  for (int i = 0; i < 9; ++i) { v[i] = ldf(&xr[lane + i * 64]); sum += v[i]; }
  #pragma unroll
  for (int off = 32; off; off >>= 1) sum += __shfl_xor(sum, off);
  float mean = sum * (1.0f / 576.0f);
  float var = 0.f;
  #pragma unroll
  for (int i = 0; i < 9; ++i) { float d = v[i] - mean; var += d * d; }
  #pragma unroll
  for (int off = 32; off; off >>= 1) var += __shfl_xor(var, off);
  float rstd = rsqrtf(var * (1.0f / 576.0f) + 1e-5f);
  u16* outr = out + row * 576;
  #pragma unroll
  for (int i = 0; i < 9; ++i) {
    int c = lane + i * 64;
    outr[c] = f2bf((v[i] - mean) * rstd * w[c] + b[c]);
  }
}

// ---------------- DMlp gather: pixelshuffle(3) + reflpad(2) + masked unfold
// chunk-local: ln2 points at chunk start (whole batches), b chunk-relative.
__constant__ int c_di[25] = {0,0,0, 1,1,1, 2,2,2, 3,3,3,3,3,3,3, 4,4,4, 5,5,5, 6,6,6};
__constant__ int c_dj[25] = {0,3,6, 1,3,5, 2,3,4, 0,1,2,3,4,5,6, 2,3,4, 1,3,5, 0,3,6};

__device__ __forceinline__ int refl168(int t) {
  return t < 0 ? -t : (t >= 168 ? 334 - t : t);
}

__global__ __launch_bounds__(256) void gather_kernel(const u16* __restrict__ ln2,
                                                     u16* __restrict__ cols) {
  int idx = blockIdx.x * 256 + threadIdx.x;
  int f = idx % 1600;
  int n_ = idx / 1600;            // b*3136 + i*56 + j  (b chunk-relative)
  int bj = n_ % 3136, b = n_ / 3136;
  int i = bj / 56, j = bj % 56;
  int p = f % 25, nf = f / 25;
  int R  = refl168(c_di[p] + 3 * i - 2);
  int Cc = refl168(c_dj[p] + 3 * j - 2);
  int h2 = R / 3, a = R - 3 * h2;
  int w2 = Cc / 3, b2 = Cc - 3 * w2;
  long src = ((long)b * 3136 + h2 * 56 + w2) * 576 + nf * 9 + a * 3 + b2;
  cols[idx] = ln2[src];
}

// ---------------- window attention, MFMA version -------------------------
// one block per (window, head); 4 waves. QK^T and PV via mfma_f32_16x16x32_bf16
__global__ __launch_bounds__(256) void attn_kernel(const u16* __restrict__ qkv,
                                                   const float* __restrict__ rpb,
                                                   u16* __restrict__ obuf) {
  int h = blockIdx.y;            // 0..5
  int wi = blockIdx.x;
  int b = wi >> 6, w = wi & 63, wr = w >> 3, wc = w & 7;
  __shared__ __align__(16) u16 Qs[64 * 104];   // [t][d] stride 104 (16B-aligned rows)
  __shared__ __align__(16) u16 Ks[64 * 104];
  __shared__ __align__(16) u16 Vt[96 * 72];    // [d][t] transposed, cols 49..63 zeroed
  __shared__ __align__(16) u16 Ps[64 * 72];    // P bf16, [i][j], pad cols exactly 0
  int tid = threadIdx.x;
  int lane = tid & 63, wv = tid >> 6;
  int quad = lane >> 4, l15 = lane & 15;
  const float scale = 0.1020620726159658f;  // 96^-0.5

  long base = ((long)b * 3136 + wr * 7 * 56 + wc * 7) * 1728 + h * 96;

  // stage Q,K: coalesced uint4 (dq fastest), conflict-free b128 writes
  for (int idx = tid; idx < 588; idx += 256) {
    int t = idx / 12, dq = idx % 12;
    int tr = t / 7, tc = t - tr * 7;
    long roff = base + (tr * 56 + tc) * 1728 + dq * 8;
    *(uint4*)&Qs[t * 104 + dq * 8] = *(const uint4*)(qkv + roff);
    *(uint4*)&Ks[t * 104 + dq * 8] = *(const uint4*)(qkv + roff + 576);
  }
  // Vt pad cols (j = 49..63) must be 0: they multiply Ps pad cols (0) in MFMA
  for (int idx = tid; idx < 96 * 15; idx += 256) {
    int d = idx / 15, t = 49 + idx % 15;
    Vt[d * 72 + t] = 0;
  }
  // stage V transposed: t-fastest lane mapping -> conflict-free u16 LDS writes
  for (int idx = tid; idx < 768; idx += 256) {
    int dq = idx >> 6, t = idx & 63;
    if (t < 49) {
      int tr = t / 7, tc = t - tr * 7;
      uint4 v = *(const uint4*)(qkv + base + (tr * 56 + tc) * 1728 + 1152 + dq * 8);
      const u16* vv = (const u16*)&v;
      #pragma unroll
      for (int kk = 0; kk < 8; ++kk) Vt[(dq * 8 + kk) * 72 + t] = vv[kk];
    }
  }
  __syncthreads();

  // ---- QK^T: wave wv owns S rows [wv*16, wv*16+16) ----
  f32x4 accS[4] = {};
  #pragma unroll
  for (int k0 = 0; k0 < 3; ++k0) {
    bf16x8 aq = *(const bf16x8*)&Qs[(wv * 16 + l15) * 104 + k0 * 32 + quad * 8];
    #pragma unroll
    for (int nt = 0; nt < 4; ++nt) {
      bf16x8 bk = *(const bf16x8*)&Ks[(nt * 16 + l15) * 104 + k0 * 32 + quad * 8];
      accS[nt] = __builtin_amdgcn_mfma_f32_16x16x32_bf16(aq, bk, accS[nt], 0, 0, 0);
    }
  }

  // ---- softmax fully in-register: row r lives in the 16 lanes of one quad ----
  #pragma unroll
  for (int r = 0; r < 4; ++r) {
    int rg = wv * 16 + quad * 4 + r;          // global window-row (0..63)
    int yi = rg / 7, xi = rg - yi * 7;
    float sv[4];
    float mx = -3e38f;
    #pragma unroll
    for (int nt = 0; nt < 4; ++nt) {
      int col = nt * 16 + l15;
      float s = accS[nt][r] * scale;
      if (rg < 49 && col < 49) {
        int yj = col / 7, xj = col - yj * 7;
        s += rpb[((yi - yj + 6) * 13 + (xi - xj + 6)) * 6 + h];
      } else {
        s = -3e38f;                            // masks pad cols AND any NaN from pad LDS
      }
      sv[nt] = s;
      mx = fmaxf(mx, s);
    }
    #pragma unroll
    for (int off = 8; off; off >>= 1) mx = fmaxf(mx, __shfl_xor(mx, off));
    float sum = 0.f;
    #pragma unroll
    for (int nt = 0; nt < 4; ++nt) { sv[nt] = __expf(sv[nt] - mx); sum += sv[nt]; }
    #pragma unroll
    for (int off = 8; off; off >>= 1) sum += __shfl_xor(sum, off);
    float inv = 1.0f / sum;
    u16* psr = Ps + rg * 72;
    #pragma unroll
    for (int nt = 0; nt < 4; ++nt) psr[nt * 16 + l15] = f2bf(sv[nt] * inv);
  }
  __syncthreads();

  // ---- PV: O[i][d] = sum_j P[i][j] * Vt[d][j], K-dim = 64 (pad zeroed) ----
  f32x4 accO[6] = {};
  #pragma unroll
  for (int k0 = 0; k0 < 2; ++k0) {
    bf16x8 ap = *(const bf16x8*)&Ps[(wv * 16 + l15) * 72 + k0 * 32 + quad * 8];
    #pragma unroll
    for (int nt = 0; nt < 6; ++nt) {
      bf16x8 bv = *(const bf16x8*)&Vt[(nt * 16 + l15) * 72 + k0 * 32 + quad * 8];
      accO[nt] = __builtin_amdgcn_mfma_f32_16x16x32_bf16(ap, bv, accO[nt], 0, 0, 0);
    }
  }
  #pragma unroll
  for (int r = 0; r < 4; ++r) {
    int rg = wv * 16 + quad * 4 + r;
    if (rg < 49) {
      int tr = rg / 7, tc = rg - tr * 7;
      long ooff = ((long)b * 3136 + (wr * 7 + tr) * 56 + wc * 7 + tc) * 576 + h * 96;
      #pragma unroll
      for (int nt = 0; nt < 6; ++nt) obuf[ooff + nt * 16 + l15] = f2bf(accO[nt][r]);
    }
  }
}

// ---------------- bf16 MFMA GEMM: C(M,N) = A(M,K) @ Bt(N,K)^T + epi ------
// tile 128x128x32, 256 threads (4 waves, 2x2), global_load_lds width-16
// staging, TRIPLE-buffered LDS (48 KB), depth-2 counted-vmcnt prefetch
// (12 loads in flight, vmcnt(8) steady state), raw s_barrier, XCD-chunked
// bijective block swizzle (T1/m204).
// Requires M % 128 == 0 and K % 32 == 0 (true for all call sites).
// N remainder: B staging row clamped to N-1, stores guarded on col < N.
// EPI: 0 = +bias ; 1 = +bias, exact GELU ; 2 = +bias, +res
template <int EPI, typename TR, typename TO>
__global__ __launch_bounds__(256) void gemm_kernel(const u16* __restrict__ A,
                                                   const u16* __restrict__ Bt,
                                                   const float* __restrict__ bias,
                                                   const TR* __restrict__ res,
                                                   TO* __restrict__ C,
                                                   int M, int N, int K) {
  __shared__ __align__(16) u16 As[3][128 * 32];
  __shared__ __align__(16) u16 Bs[3][128 * 32];

  // XCD-chunked bijective swizzle: HW assigns xcd = flat % 8 round-robin;
  // remap so each XCD owns a contiguous range of the logical (n-fastest)
  // grid -> all N-blocks of an M-panel share one XCD's L2 (A-panel reuse).
  int nwg = gridDim.x * gridDim.y;
  int flat = blockIdx.y * gridDim.x + blockIdx.x;
  int q = nwg >> 3, r = nwg & 7;
  int xcd = flat & 7, loc = flat >> 3;
  int newflat = ((xcd < r) ? xcd * (q + 1) : r * (q + 1) + (xcd - r) * q) + loc;
  int nblk = newflat % gridDim.x, mblk = newflat / gridDim.x;
  int n0 = nblk * 128;
  int m0 = mblk * 128;

  int tid = threadIdx.x;
  int lane = tid & 63, wv = tid >> 6;
  int quad = lane >> 4, l15 = lane & 15;
  int wr2 = wv >> 1, wc2 = wv & 1;            // wave -> 64x64 quadrant
  f32x4 acc[4][4] = {};

  // per-thread staging chunks (16B): chunk = it*256 + tid ; r = chunk>>2 ; kc = chunk&3
  int rA0 = tid >> 2, rA1 = (256 + tid) >> 2;
  int kc0 = (tid & 3) * 8;
  int rB0 = n0 + rA0; if (rB0 > N - 1) rB0 = N - 1;
  int rB1 = n0 + rA1; if (rB1 > N - 1) rB1 = N - 1;
  const u16* gA0 = A + (long)(m0 + rA0) * K + kc0;
  const u16* gA1 = A + (long)(m0 + rA1) * K + kc0;
  const u16* gB0 = Bt + (long)rB0 * K + kc0;
  const u16* gB1 = Bt + (long)rB1 * K + kc0;
  int lo0 = (wv * 64) * 8, lo1 = (256 + wv * 64) * 8;  // wave-uniform LDS bases

  int nt = K >> 5;
  #define STAGE(bufi, kk) do {                    \
    load_lds16(gA0 + (kk), &As[bufi][lo0]);       \
    load_lds16(gA1 + (kk), &As[bufi][lo1]);       \
    load_lds16(gB0 + (kk), &Bs[bufi][lo0]);       \
    load_lds16(gB1 + (kk), &Bs[bufi][lo1]); } while (0)

  auto compute = [&](int cur) {
    bf16x8 a[4], bfr[4];
    const u16* as = &As[cur][(wr2 * 64 + l15) * 32 + quad * 8];
    const u16* bs = &Bs[cur][(wc2 * 64 + l15) * 32 + quad * 8];
    #pragma unroll
    for (int mi = 0; mi < 4; ++mi) a[mi] = *(const bf16x8*)(as + mi * 512);
    #pragma unroll
    for (int ni = 0; ni < 4; ++ni) bfr[ni] = *(const bf16x8*)(bs + ni * 512);
    #pragma unroll
    for (int mi = 0; mi < 4; ++mi)
      #pragma unroll
      for (int ni = 0; ni < 4; ++ni)
        acc[mi][ni] = __builtin_amdgcn_mfma_f32_16x16x32_bf16(a[mi], bfr[ni], acc[mi][ni], 0, 0, 0);
  };

  // prologue: stage tiles 0 and 1 (8 loads in flight)
  STAGE(0, 0);
  STAGE(1, 32);
  int cur = 0, nx2 = 2;
  for (int t = 0; t < nt; ++t) {
    if (t + 2 < nt) {
      STAGE(nx2, (t + 2) * 32);                 // 12 in flight
      asm volatile("s_waitcnt vmcnt(8)" ::: "memory");   // tile-t done
    } else if (t + 1 < nt) {
      asm volatile("s_waitcnt vmcnt(4)" ::: "memory");   // drain: t done, t+1 flying
    } else {
      asm volatile("s_waitcnt vmcnt(0)" ::: "memory");   // last tile done
    }
    __builtin_amdgcn_s_barrier();               // all waves' tile-t loads landed
    compute(cur);
    __builtin_amdgcn_s_barrier();               // readers of buf[cur] done before
                                                // iter t+1 stages tile t+3 into it
    cur = cur + 1; if (cur == 3) cur = 0;
    nx2 = nx2 + 1; if (nx2 == 3) nx2 = 0;
  }
  #undef STAGE

  #pragma unroll
  for (int mi = 0; mi < 4; ++mi)
    #pragma unroll
    for (int ni = 0; ni < 4; ++ni) {
      int col = n0 + wc2 * 64 + ni * 16 + l15;
      if (col < N) {
        float bz = bias[col];
        #pragma unroll
        for (int rr = 0; rr < 4; ++rr) {
          int row = m0 + wr2 * 64 + mi * 16 + quad * 4 + rr;
          float v = acc[mi][ni][rr] + bz;
          if (EPI == 1) v = 0.5f * v * (1.0f + erff(v * 0.70710678118654752f));
          if (EPI == 2) v += ldf(&res[(long)row * N + col]);
          long off = (long)row * N + col;
          if (sizeof(TO) == 2) ((u16*)C)[off] = f2bf(v);
          else                 ((float*)C)[off] = v;
        }
      }
    }
}

// ---------------- host launch -------------------------------------------
// Inputs fp32, OUTPUT FP32. ws peak ~90.6 MB.
// x1 (phase-1 output) lives in d_out as f32: proj writes it, phase-2 LN
// reads it, fc2 reads it as residual and overwrites in place (each element
// touched exactly once, read-before-write in the same thread; phase 1 fully
// rewrites d_out before phase 2 reads -> graph-replay idempotent).
extern "C" void kernel_launch(void* const* d_in, const int* in_sizes, int n_in,
                              void* d_out, int out_size, void* d_ws, size_t ws_size,
                              hipStream_t stream) {
  const float* x      = (const float*)d_in[0];
  const float* n1w    = (const float*)d_in[1];
  const float* n1b    = (const float*)d_in[2];
  const float* qkv_w  = (const float*)d_in[3];
  const float* qkv_b  = (const float*)d_in[4];
  const float* rpb    = (const float*)d_in[5];
  const float* proj_w = (const float*)d_in[6];
  const float* proj_b = (const float*)d_in[7];
  const float* n2w    = (const float*)d_in[8];
  const float* n2b    = (const float*)d_in[9];
  const float* fc1_w  = (const float*)d_in[10];
  const float* fc1_b  = (const float*)d_in[11];
  const float* fc2_w  = (const float*)d_in[12];
  const float* fc2_b  = (const float*)d_in[13];

  char* ws = (char*)d_ws;
  u16* wt_qkv  = (u16*)(ws + 0);           // 1728x576
  u16* wt_proj = (u16*)(ws + 1990656);     // 576x576
  u16* wt_fc1  = (u16*)(ws + 2654208);     // 1024x1600
  u16* wt_fc2  = (u16*)(ws + 5931008);     // 576x1024
  char* qkvpool = ws + 7110656;            // 43,352,064 B (ph1 qkvb / ph2 colsb)
  char* lnpool  = ws + 50462720;           // 14,450,688 B (ph1 lnb / ph2 ln2b)
  char* hpool   = ws + 64913408;           // 25,690,112 B (ph2 hb) end 90,603,520
  float* x1 = (float*)d_out;               // 25088x576 f32

  transpose_kernel<<<3888, 256, 0, stream>>>(qkv_w, wt_qkv, 576, 1728);
  transpose_kernel<<<1296, 256, 0, stream>>>(proj_w, wt_proj, 576, 576);
  transpose_kernel<<<6400, 256, 0, stream>>>(fc1_w, wt_fc1, 1600, 1024);
  transpose_kernel<<<2304, 256, 0, stream>>>(fc2_w, wt_fc2, 1024, 576);

  // ---------- phase 1: two halves of 4 batches (12544 rows each) ----------
  for (int h = 0; h < 2; ++h) {
    const long r0 = (long)h * 12544;
    u16* lnb  = (u16*)lnpool;          // ln1 out, then reused as attn out
    u16* qkvb = (u16*)qkvpool;
    ln_kernel<float><<<3136, 256, 0, stream>>>(x + r0 * 576, n1w, n1b, lnb);
    gemm_kernel<0, float, u16><<<dim3(14, 98), 256, 0, stream>>>(
        lnb, wt_qkv, qkv_b, (const float*)nullptr, qkvb, 12544, 1728, 576);
    attn_kernel<<<dim3(256, 6), 256, 0, stream>>>(qkvb, rpb, lnb);
    gemm_kernel<2, float, float><<<dim3(5, 98), 256, 0, stream>>>(
        lnb, wt_proj, proj_b, x + r0 * 576, x1 + r0 * 576, 12544, 576, 576);
  }

  // ---------- phase 2: two halves of 4 batches (12544 rows each) ----------
  for (int q = 0; q < 2; ++q) {
    const long r0 = (long)q * 12544;
    u16* ln2b  = (u16*)lnpool;                    // 14,450,688 B
    u16* colsb = (u16*)qkvpool;                   // 40,140,800 B
    u16* hb    = (u16*)hpool;                     // 25,690,112 B
    ln_kernel<float><<<3136, 256, 0, stream>>>(x1 + r0 * 576, n2w, n2b, ln2b);
    gather_kernel<<<78400, 256, 0, stream>>>(ln2b, colsb);
    gemm_kernel<1, float, u16><<<dim3(8, 98), 256, 0, stream>>>(
        colsb, wt_fc1, fc1_b, (const float*)nullptr, hb, 12544, 1024, 1600);
    gemm_kernel<2, float, float><<<dim3(5, 98), 256, 0, stream>>>(
        hb, wt_fc2, fc2_b, x1 + r0 * 576, x1 + r0 * 576, 12544, 576, 1024);
  }
}